// Round 7
// baseline (1375.573 us; speedup 1.0000x reference)
//
#include <hip/hip_runtime.h>
#include <math.h>

#define H_ 256
#define W_ 320
#define C_ 28
#define HWC (H_ * W_ * C_)          // 2293760 elems per batch
#define PI_D 3.14159265358979323846

__device__ __forceinline__ float gelu_f(float x) {
    return 0.5f * x * (1.0f + erff(x * 0.7071067811865476f));
}

// ---------------------------------------------------------------------------
// DCT basis matrices, stored TRANSPOSED for coalesced per-lane access
// ---------------------------------------------------------------------------
__global__ void gen_mats(float* __restrict__ dhT, float* __restrict__ dwT,
                         float* __restrict__ dihT, float* __restrict__ diwT) {
    int i = blockIdx.x * 256 + threadIdx.x;
    if (i < 256 * 256) {
        int k = i >> 8, n = i & 255;
        double c = cos(PI_D * (2.0 * n + 1.0) * k / 512.0);
        dhT[n * 256 + k] = (float)(2.0 * c);
        dihT[k * 256 + n] = (float)(k == 0 ? (1.0 / 512.0) : c / 256.0);
    }
    if (i < 320 * 320) {
        int k = i / 320, n = i - k * 320;
        double c = cos(PI_D * (2.0 * n + 1.0) * k / 640.0);
        dwT[n * 320 + k] = (float)(2.0 * c);
        diwT[k * 320 + n] = (float)(k == 0 ? (1.0 / 640.0) : c / 320.0);
    }
}

// G[h][c][c'] = sum_d wq[c, h*28+d] * wkv[c', h*28+d] * 28^-0.5   (local attn)
__global__ void gen_locG(const float* __restrict__ wq, const float* __restrict__ wkv,
                         float* __restrict__ G) {
    int i = blockIdx.x * 256 + threadIdx.x;  // 6272
    if (i < 6272) {
        int h = i / 784, r = i - h * 784;
        int c = r / 28, cp = r - c * 28;
        float s = 0.f;
        #pragma unroll
        for (int d = 0; d < 28; ++d)
            s += wq[c * 224 + h * 28 + d] * wkv[cp * 448 + h * 28 + d];
        G[i] = s * 0.18898223650461363f;  // 28^-0.5
    }
}

// M2[h][c][co] = sum_d Wv_h[c][d] * pw_h[d][co]   (fold V-proj into out-proj)
__global__ void gen_locM2(const float* __restrict__ wkv, const float* __restrict__ pw,
                          float* __restrict__ M2) {
    int i = blockIdx.x * 256 + threadIdx.x;  // 6272
    if (i < 6272) {
        int h = i / 784, r = i - h * 784;
        int c = r / 28, co = r - c * 28;
        float s = 0.f;
        #pragma unroll
        for (int d = 0; d < 28; ++d)
            s += wkv[c * 448 + 224 + h * 28 + d] * pw[(h * 28 + d) * 28 + co];
        M2[i] = s;
    }
}

// posT[h][j][i] = pos[h][i][j]
__global__ void gen_posT(const float* __restrict__ pos, float* __restrict__ posT) {
    int id = blockIdx.x * 256 + threadIdx.x;   // 32768
    int h = id >> 12, r = id & 4095, i = r >> 6, j = r & 63;
    posT[(h << 12) + (j << 6) + i] = pos[id];
}

// ---------------------------------------------------------------------------
// Strided matrix apply with TRANSPOSED matrix: out[m,c] = sum_k matT[k*M+m] in[k,c]
// ---------------------------------------------------------------------------
__global__ void dct_apply(const float* __restrict__ matT, const float* __restrict__ in,
                          float* __restrict__ out, int M, int Kd, int inner_n,
                          int stride_i_in, int kstride_in,
                          int stride_i_out, int mstride_out) {
    extern __shared__ float s_in[];  // [Kd][28]
    int bidx = blockIdx.x;
    int o = bidx / inner_n;
    int ii = bidx - o * inner_n;
    const float* bin = in + (size_t)o * HWC + (size_t)ii * stride_i_in;
    float* bout = out + (size_t)o * HWC + (size_t)ii * stride_i_out;
    int tot = Kd * C_;
    for (int e = threadIdx.x; e < tot; e += blockDim.x) {
        int k = e / C_;
        int c = e - k * C_;
        s_in[e] = bin[k * kstride_in + c];
    }
    __syncthreads();
    int m = threadIdx.x;
    if (m < M) {
        float4 acc[7];
        #pragma unroll
        for (int q = 0; q < 7; ++q) acc[q] = make_float4(0.f, 0.f, 0.f, 0.f);
        for (int k = 0; k < Kd; ++k) {
            float d = matT[k * M + m];   // coalesced across lanes
            const float4* row = (const float4*)(s_in + k * C_);
            #pragma unroll
            for (int q = 0; q < 7; ++q) {
                float4 v = row[q];
                acc[q].x += d * v.x; acc[q].y += d * v.y;
                acc[q].z += d * v.z; acc[q].w += d * v.w;
            }
        }
        float4* orow = (float4*)(bout + (size_t)m * mstride_out);
        #pragma unroll
        for (int q = 0; q < 7; ++q) orow[q] = acc[q];
    }
}

// ---------------------------------------------------------------------------
// Spectral DCT attention — Gram-matrix formulation, 256 threads / patch.
// (unchanged)
// ---------------------------------------------------------------------------
__global__ __launch_bounds__(256, 4) void spec_attn(
    const float* __restrict__ xdct, const float* __restrict__ wq,
    const float* __restrict__ wk, const float* __restrict__ wv,
    const float* __restrict__ rescale, const float* __restrict__ pw,
    const float* __restrict__ pb, float* __restrict__ xlow) {
    __shared__ __align__(16) float smem[9780];
    float* sX  = smem;             // [64][29] = 1856
    float* sG  = sX + 1856;        // 784
    float* sWq = sG + 784;         // 784
    float* sWk = sWq + 784;        // 784
    float* sWv = sWk + 784;        // 784
    float* sPw = sWv + 784;        // 784
    float* sA  = sPw + 784;        // 784
    float* sB  = sA + 784;         // 784
    float* sP  = sB + 784;         // [28][29] = 812
    float* sM3 = sP + 812;         // 784
    float* sR  = sM3 + 784;        // 784
    float* sqn = sR + 784;         // 28
    float* skn = sqn + 28;         // 28

    int t = threadIdx.x;
    int blk = blockIdx.x;
    int b = blk / 1280;
    int r = blk - b * 1280;
    int bh = r / 40;
    int bw = r - bh * 40;
    const float* base = xdct + ((size_t)((b * 256 + bh * 8) * 320 + bw * 8)) * 28;

    for (int e = t; e < 1792; e += 256) {
        int m = e / 28, c = e - m * 28;
        sX[m * 29 + c] = base[((m >> 3) * 320 + (m & 7)) * 28 + c];
    }
    for (int e = t; e < 784; e += 256) sR[e] = 0.f;
    __syncthreads();

    for (int e = t; e < 784; e += 256) {
        int c = e / 28, c2 = e - c * 28;
        float a0 = 0.f, a1 = 0.f, a2 = 0.f, a3 = 0.f;
        #pragma unroll 4
        for (int m = 0; m < 64; m += 4) {
            a0 += sX[m * 29 + c] * sX[m * 29 + c2];
            a1 += sX[(m + 1) * 29 + c] * sX[(m + 1) * 29 + c2];
            a2 += sX[(m + 2) * 29 + c] * sX[(m + 2) * 29 + c2];
            a3 += sX[(m + 3) * 29 + c] * sX[(m + 3) * 29 + c2];
        }
        sG[e] = (a0 + a1) + (a2 + a3);
    }
    __syncthreads();

    for (int h = 0; h < 8; ++h) {
        for (int e = t; e < 784; e += 256) {
            int c = e / 28, d = e - c * 28;
            sWq[e] = wq[c * 224 + h * 28 + d];
            sWk[e] = wk[c * 224 + h * 28 + d];
            sWv[e] = wv[c * 224 + h * 28 + d];
            sPw[e] = pw[h * 784 + e];
        }
        __syncthreads();
        for (int tile = t; tile < 392; tile += 256) {
            int isB = tile >= 196;
            int tt = isB ? tile - 196 : tile;
            int c = tt / 7, d4 = (tt - c * 7) * 4;
            const float* W = isB ? sWk : sWq;
            float ax = 0.f, ay = 0.f, az = 0.f, aw = 0.f;
            #pragma unroll
            for (int c2 = 0; c2 < 28; ++c2) {
                float g = sG[c * 28 + c2];
                const float4 w4 = *(const float4*)(W + c2 * 28 + d4);
                ax += g * w4.x; ay += g * w4.y; az += g * w4.z; aw += g * w4.w;
            }
            float* dst = (isB ? sB : sA) + c * 28 + d4;
            *(float4*)dst = make_float4(ax, ay, az, aw);
        }
        __syncthreads();
        if (t < 28) {
            float s = 0.f;
            #pragma unroll
            for (int c = 0; c < 28; ++c) s += sWq[c * 28 + t] * sA[c * 28 + t];
            sqn[t] = fmaxf(sqrtf(s), 1e-12f);
        } else if (t >= 32 && t < 60) {
            int d = t - 32;
            float s = 0.f;
            #pragma unroll
            for (int c = 0; c < 28; ++c) s += sWk[c * 28 + d] * sB[c * 28 + d];
            skn[d] = fmaxf(sqrtf(s), 1e-12f);
        }
        __syncthreads();
        float resc = rescale[h];
        for (int e = t; e < 784; e += 256) {
            int d = e / 28, ee = e - d * 28;
            float s = 0.f;
            #pragma unroll
            for (int c = 0; c < 28; ++c) s += sWq[c * 28 + d] * sB[c * 28 + ee];
            sP[d * 29 + ee] = __expf(s * resc / (sqn[d] * skn[ee]));
        }
        __syncthreads();
        if (t < 28) {
            float s = 0.f;
            #pragma unroll
            for (int ee = 0; ee < 28; ++ee) s += sP[t * 29 + ee];
            float inv = 1.0f / s;
            #pragma unroll
            for (int ee = 0; ee < 28; ++ee) sP[t * 29 + ee] *= inv;
        }
        __syncthreads();
        for (int id = t; id < 784; id += 256) {
            int ee = id / 28, co = id - ee * 28;
            float a0 = 0.f, a1 = 0.f;
            #pragma unroll 2
            for (int d = 0; d < 28; d += 2) {
                a0 += sP[d * 29 + ee] * sPw[d * 28 + co];
                a1 += sP[(d + 1) * 29 + ee] * sPw[(d + 1) * 28 + co];
            }
            sM3[id] = a0 + a1;
        }
        __syncthreads();
        for (int id = t; id < 784; id += 256) {
            int c = id / 28, co = id - c * 28;
            float a0 = 0.f, a1 = 0.f;
            #pragma unroll 2
            for (int e = 0; e < 28; e += 2) {
                a0 += sWv[c * 28 + e] * sM3[e * 28 + co];
                a1 += sWv[c * 28 + e + 1] * sM3[(e + 1) * 28 + co];
            }
            sR[id] += a0 + a1;
        }
        __syncthreads();
    }
    float* outp = xlow + ((size_t)((b * 256 + bh * 8) * 320 + bw * 8)) * 28;
    for (int id = t; id < 1792; id += 256) {
        int m = id / 28, co = id - m * 28;
        float s = pb[co];
        #pragma unroll
        for (int c = 0; c < 28; ++c) s += sX[m * 29 + c] * sR[c * 28 + co];
        outp[((m >> 3) * 320 + (m & 7)) * 28 + co] = s;
    }
}

// ---------------------------------------------------------------------------
// y1 = gelu(pointwise-conv(x_dct))
// ---------------------------------------------------------------------------
__global__ __launch_bounds__(256) void hf_pw1(const float* __restrict__ xdct,
                                              const float* __restrict__ w,
                                              float* __restrict__ y1) {
    __shared__ float s_w[28][29];
    __shared__ float s_x[256][29];
    int t = threadIdx.x;
    for (int e = t; e < 784; e += 256) s_w[e / 28][e % 28] = w[e];
    size_t p0 = (size_t)blockIdx.x * 256;
    const float* src = xdct + p0 * 28;
    for (int e = t; e < 7168; e += 256) {
        int p = e / 28, c = e - p * 28;
        s_x[p][c] = src[e];
    }
    __syncthreads();
    float o[28];
    #pragma unroll
    for (int oo = 0; oo < 28; ++oo) {
        float a = 0.f;
        #pragma unroll
        for (int c = 0; c < 28; ++c) a += s_w[oo][c] * s_x[t][c];
        o[oo] = gelu_f(a);
    }
    __syncthreads();
    #pragma unroll
    for (int oo = 0; oo < 28; ++oo) s_x[t][oo] = o[oo];
    __syncthreads();
    float* dst = y1 + p0 * 28;
    for (int e = t; e < 7168; e += 256) {
        int p = e / 28, c = e - p * 28;
        dst[e] = s_x[p][c];
    }
}

// ---------------------------------------------------------------------------
// Depthwise 3x3 + gelu + residual + pointwise2 + gelu + residual + coef blend
// ---------------------------------------------------------------------------
__global__ __launch_bounds__(256) void hf_combine(
    const float* __restrict__ y1, const float* __restrict__ xdct,
    const float* __restrict__ xlow, const float* __restrict__ dww,
    const float* __restrict__ pw2, const float* __restrict__ coef,
    float* __restrict__ xout) {
    __shared__ float s_dw[252];
    __shared__ float s_pw[28][29];
    int t = threadIdx.x;
    for (int e = t; e < 252; e += 256) s_dw[e] = dww[e];
    for (int e = t; e < 784; e += 256) s_pw[e / 28][e % 28] = pw2[e];
    __syncthreads();
    int pix = blockIdx.x * 256 + t;
    int b = pix / 81920;
    int rem = pix - b * 81920;
    int y = rem / 320;
    int xx = rem - y * 320;
    float conv[28];
    #pragma unroll
    for (int c = 0; c < 28; ++c) conv[c] = 0.f;
    for (int dy = 0; dy < 3; ++dy) {
        int yy = y + dy - 1;
        if (yy < 0 || yy >= 256) continue;
        for (int dx = 0; dx < 3; ++dx) {
            int xq = xx + dx - 1;
            if (xq < 0 || xq >= 320) continue;
            const float* rp = y1 + ((size_t)(b * 256 + yy) * 320 + xq) * 28;
            #pragma unroll
            for (int c = 0; c < 28; ++c) conv[c] += s_dw[c * 9 + dy * 3 + dx] * rp[c];
        }
    }
    const float* xd = xdct + (size_t)pix * 28;
    const float* xl = xlow + (size_t)pix * 28;
    float xdr[28], xcv[28];
    #pragma unroll
    for (int c = 0; c < 28; ++c) {
        xdr[c] = xd[c];
        xcv[c] = gelu_f(conv[c]) + xdr[c];
    }
    float cf = coef[rem];
    float omc = 1.0f - cf;
    float* xo = xout + (size_t)pix * 28;
    #pragma unroll
    for (int oo = 0; oo < 28; ++oo) {
        float a = 0.f;
        #pragma unroll
        for (int c = 0; c < 28; ++c) a += s_pw[oo][c] * xcv[c];
        float xh = gelu_f(a) + xcv[oo];
        xo[oo] = cf * xl[oo] + omc * xh + xdr[oo];
    }
}

// ---------------------------------------------------------------------------
// Local windowed attention v5: 128 threads = 2 waves = 2 windows, 8 heads/wave.
// Live-register budget engineered to <=128 (no xw array: own row re-read from
// LDS per head). G/M2 wave-uniform from global; posT coalesced scalar loads.
// ---------------------------------------------------------------------------
__global__ __launch_bounds__(128, 4) void local_attn(
    const float* __restrict__ x, const float* __restrict__ G,
    const float* __restrict__ M2, const float* __restrict__ posT,
    const float* __restrict__ pb, float* __restrict__ outloc) {
    __shared__ float s_xw[2][1792];    // 14336 B
    int t = threadIdx.x;
    int wave = t >> 6, lane = t & 63;
    int win = blockIdx.x * 2 + wave;
    int b = win / 1280;
    int r = win - b * 1280;
    int wh = r / 40, wwi = r - wh * 40;
    int p_ = lane >> 3, q_ = lane & 7;
    const float* rowp = x + ((size_t)((b * 256 + wh * 8 + p_) * 320) + wwi * 8 + q_) * 28;
    float* sxm = s_xw[wave] + lane * 28;
    #pragma unroll
    for (int q4 = 0; q4 < 7; ++q4)
        ((float4*)sxm)[q4] = ((const float4*)rowp)[q4];
    __syncthreads();
    float acc[28];
    #pragma unroll
    for (int c = 0; c < 28; ++c) acc[c] = 0.f;
    const float* swbase = s_xw[wave];
    for (int h = 0; h < 8; ++h) {
        // ---- t1 = own_row @ G_h  (own row re-read from LDS; G wave-uniform) ----
        float t1[28];
        #pragma unroll
        for (int d = 0; d < 28; ++d) t1[d] = 0.f;
        const float* gh = G + h * 784;
        #pragma unroll
        for (int c = 0; c < 28; ++c) {
            float xc = sxm[c];
            const float4* gr = (const float4*)(gh + c * 28);
            #pragma unroll
            for (int q4 = 0; q4 < 7; ++q4) {
                float4 g4 = gr[q4];
                t1[4 * q4] += xc * g4.x; t1[4 * q4 + 1] += xc * g4.y;
                t1[4 * q4 + 2] += xc * g4.z; t1[4 * q4 + 3] += xc * g4.w;
            }
        }
        // ---- single-pass no-max softmax: S, u = sum_j exp(s_j) xw_j ----
        float S = 0.f;
        float u[28];
        #pragma unroll
        for (int c = 0; c < 28; ++c) u[c] = 0.f;
        const float* pbase = posT + (h << 12) + lane;
        for (int j = 0; j < 64; ++j) {
            const float4* rj = (const float4*)(swbase + j * 28);
            float4 r0 = rj[0], r1 = rj[1], r2 = rj[2], r3 = rj[3];
            float4 r4 = rj[4], r5 = rj[5], r6 = rj[6];
            float a0 = t1[0] * r0.x + t1[4] * r1.x + t1[8] * r2.x + t1[12] * r3.x
                     + t1[16] * r4.x + t1[20] * r5.x + t1[24] * r6.x;
            float a1 = t1[1] * r0.y + t1[5] * r1.y + t1[9] * r2.y + t1[13] * r3.y
                     + t1[17] * r4.y + t1[21] * r5.y + t1[25] * r6.y;
            float a2 = t1[2] * r0.z + t1[6] * r1.z + t1[10] * r2.z + t1[14] * r3.z
                     + t1[18] * r4.z + t1[22] * r5.z + t1[26] * r6.z;
            float a3 = t1[3] * r0.w + t1[7] * r1.w + t1[11] * r2.w + t1[15] * r3.w
                     + t1[19] * r4.w + t1[23] * r5.w + t1[27] * r6.w;
            float s = ((a0 + a1) + (a2 + a3)) + pbase[j << 6];
            float p = __expf(s);
            S += p;
            u[0] += p * r0.x; u[1] += p * r0.y; u[2] += p * r0.z; u[3] += p * r0.w;
            u[4] += p * r1.x; u[5] += p * r1.y; u[6] += p * r1.z; u[7] += p * r1.w;
            u[8] += p * r2.x; u[9] += p * r2.y; u[10] += p * r2.z; u[11] += p * r2.w;
            u[12] += p * r3.x; u[13] += p * r3.y; u[14] += p * r3.z; u[15] += p * r3.w;
            u[16] += p * r4.x; u[17] += p * r4.y; u[18] += p * r4.z; u[19] += p * r4.w;
            u[20] += p * r5.x; u[21] += p * r5.y; u[22] += p * r5.z; u[23] += p * r5.w;
            u[24] += p * r6.x; u[25] += p * r6.y; u[26] += p * r6.z; u[27] += p * r6.w;
        }
        float inv = 1.0f / S;
        // ---- acc += (u*inv) @ M2_h  (M2 wave-uniform from global) ----
        const float* mh = M2 + h * 784;
        #pragma unroll
        for (int c = 0; c < 28; ++c) {
            float uc = u[c] * inv;
            const float4* mr = (const float4*)(mh + c * 28);
            #pragma unroll
            for (int q4 = 0; q4 < 7; ++q4) {
                float4 m4 = mr[q4];
                acc[4 * q4] += uc * m4.x; acc[4 * q4 + 1] += uc * m4.y;
                acc[4 * q4 + 2] += uc * m4.z; acc[4 * q4 + 3] += uc * m4.w;
            }
        }
    }
    float* op = outloc + ((size_t)((b * 256 + wh * 8 + p_) * 320) + wwi * 8 + q_) * 28;
    #pragma unroll
    for (int q4 = 0; q4 < 7; ++q4) {
        float4 o4;
        o4.x = acc[4 * q4] + pb[4 * q4];
        o4.y = acc[4 * q4 + 1] + pb[4 * q4 + 1];
        o4.z = acc[4 * q4 + 2] + pb[4 * q4 + 2];
        o4.w = acc[4 * q4 + 3] + pb[4 * q4 + 3];
        ((float4*)op)[q4] = o4;
    }
}

// ---------------------------------------------------------------------------
// Fusion
// ---------------------------------------------------------------------------
__global__ __launch_bounds__(256) void fuse_k(
    const float* __restrict__ fd, const float* __restrict__ loc,
    const float* __restrict__ w, const float* __restrict__ bias,
    float* __restrict__ out) {
    __shared__ float s_w[28][57];
    __shared__ float s_b[28];
    int t = threadIdx.x;
    for (int e = t; e < 28 * 56; e += 256) s_w[e / 56][e % 56] = w[e];
    if (t < 28) s_b[t] = bias[t];
    __syncthreads();
    size_t pix = (size_t)blockIdx.x * 256 + t;
    const float* f = fd + pix * 28;
    const float* l = loc + pix * 28;
    float fr[28], lr[28];
    #pragma unroll
    for (int c = 0; c < 28; ++c) { fr[c] = f[c]; lr[c] = l[c]; }
    float* o = out + pix * 28;
    #pragma unroll
    for (int oo = 0; oo < 28; ++oo) {
        float a = s_b[oo];
        #pragma unroll
        for (int c = 0; c < 28; ++c) a += s_w[oo][c] * fr[c] + s_w[oo][28 + c] * lr[c];
        o[oo] = a;
    }
}

extern "C" void kernel_launch(void* const* d_in, const int* in_sizes, int n_in,
                              void* d_out, int out_size, void* d_ws, size_t ws_size,
                              hipStream_t stream) {
    const float* x         = (const float*)d_in[0];
    const float* spec_wq   = (const float*)d_in[1];
    const float* spec_wk   = (const float*)d_in[2];
    const float* spec_wv   = (const float*)d_in[3];
    const float* spec_resc = (const float*)d_in[4];
    const float* spec_pw   = (const float*)d_in[5];
    const float* spec_pb   = (const float*)d_in[6];
    const float* hf1_pw_w  = (const float*)d_in[7];
    const float* hf1_dw_w  = (const float*)d_in[8];
    const float* hf2_pw_w  = (const float*)d_in[9];
    const float* coef_emb  = (const float*)d_in[10];
    const float* loc_wq    = (const float*)d_in[11];
    const float* loc_wkv   = (const float*)d_in[12];
    const float* loc_pos   = (const float*)d_in[13];
    const float* loc_pw    = (const float*)d_in[14];
    const float* loc_pb    = (const float*)d_in[15];
    const float* fus_w     = (const float*)d_in[16];
    const float* fus_b     = (const float*)d_in[17];

    float* ws = (float*)d_ws;
    float* mDH  = ws;                       // 65536
    float* mDW  = mDH + 65536;              // 102400
    float* mDIH = mDW + 102400;             // 65536
    float* mDIW = mDIH + 65536;             // 102400
    float* locG = mDIW + 102400;            // 6272
    float* locM2 = locG + 6272;             // 6272
    float* posT = locM2 + 6272;             // 32768
    float* bufA = posT + 32768;             // 2*HWC each
    float* bufB = bufA + 2 * HWC;
    float* bufC = bufB + 2 * HWC;
    float* bufD = bufC + 2 * HWC;

    gen_mats<<<400, 256, 0, stream>>>(mDH, mDW, mDIH, mDIW);
    gen_locG<<<25, 256, 0, stream>>>(loc_wq, loc_wkv, locG);
    gen_locM2<<<25, 256, 0, stream>>>(loc_wkv, loc_pw, locM2);
    gen_posT<<<128, 256, 0, stream>>>(loc_pos, posT);

    // forward DCT
    dct_apply<<<640, 256, 256 * 28 * 4, stream>>>(mDH, x, bufA,
        256, 256, 320, 28, 8960, 28, 8960);
    dct_apply<<<512, 320, 320 * 28 * 4, stream>>>(mDW, bufA, bufB,
        320, 320, 256, 8960, 28, 8960, 28);

    // spectral attention -> x_low (bufC)
    spec_attn<<<2560, 256, 0, stream>>>(bufB, spec_wq, spec_wk, spec_wv,
                                        spec_resc, spec_pw, spec_pb, bufC);
    // high-frequency path
    hf_pw1<<<640, 256, 0, stream>>>(bufB, hf1_pw_w, bufA);
    hf_combine<<<640, 256, 0, stream>>>(bufA, bufB, bufC, hf1_dw_w, hf2_pw_w,
                                        coef_emb, bufD);
    // inverse DCT: x_out (bufD) -> out_fd (bufC)
    dct_apply<<<640, 256, 256 * 28 * 4, stream>>>(mDIH, bufD, bufA,
        256, 256, 320, 28, 8960, 28, 8960);
    dct_apply<<<512, 320, 320 * 28 * 4, stream>>>(mDIW, bufA, bufC,
        320, 320, 256, 8960, 28, 8960, 28);

    // local windowed attention -> bufB
    local_attn<<<1280, 128, 0, stream>>>(x, locG, locM2, posT, loc_pb, bufB);

    // fusion -> output
    fuse_k<<<640, 256, 0, stream>>>(bufC, bufB, fus_w, fus_b, (float*)d_out);
}

// Round 8
// 1225.960 us; speedup vs baseline: 1.1220x; 1.1220x over previous
//
#include <hip/hip_runtime.h>
#include <math.h>

#define H_ 256
#define W_ 320
#define C_ 28
#define HWC (H_ * W_ * C_)          // 2293760 elems per batch
#define PI_D 3.14159265358979323846

__device__ __forceinline__ float gelu_f(float x) {
    return 0.5f * x * (1.0f + erff(x * 0.7071067811865476f));
}

// ---------------------------------------------------------------------------
// DCT basis matrices, stored TRANSPOSED for coalesced per-lane access
// ---------------------------------------------------------------------------
__global__ void gen_mats(float* __restrict__ dhT, float* __restrict__ dwT,
                         float* __restrict__ dihT, float* __restrict__ diwT) {
    int i = blockIdx.x * 256 + threadIdx.x;
    if (i < 256 * 256) {
        int k = i >> 8, n = i & 255;
        double c = cos(PI_D * (2.0 * n + 1.0) * k / 512.0);
        dhT[n * 256 + k] = (float)(2.0 * c);
        dihT[k * 256 + n] = (float)(k == 0 ? (1.0 / 512.0) : c / 256.0);
    }
    if (i < 320 * 320) {
        int k = i / 320, n = i - k * 320;
        double c = cos(PI_D * (2.0 * n + 1.0) * k / 640.0);
        dwT[n * 320 + k] = (float)(2.0 * c);
        diwT[k * 320 + n] = (float)(k == 0 ? (1.0 / 640.0) : c / 320.0);
    }
}

// G[h][c][c'] = sum_d wq[c, h*28+d] * wkv[c', h*28+d] * 28^-0.5   (local attn)
__global__ void gen_locG(const float* __restrict__ wq, const float* __restrict__ wkv,
                         float* __restrict__ G) {
    int i = blockIdx.x * 256 + threadIdx.x;  // 6272
    if (i < 6272) {
        int h = i / 784, r = i - h * 784;
        int c = r / 28, cp = r - c * 28;
        float s = 0.f;
        #pragma unroll
        for (int d = 0; d < 28; ++d)
            s += wq[c * 224 + h * 28 + d] * wkv[cp * 448 + h * 28 + d];
        G[i] = s * 0.18898223650461363f;  // 28^-0.5
    }
}

// M2[h][c][co] = sum_d Wv_h[c][d] * pw_h[d][co]   (fold V-proj into out-proj)
__global__ void gen_locM2(const float* __restrict__ wkv, const float* __restrict__ pw,
                          float* __restrict__ M2) {
    int i = blockIdx.x * 256 + threadIdx.x;  // 6272
    if (i < 6272) {
        int h = i / 784, r = i - h * 784;
        int c = r / 28, co = r - c * 28;
        float s = 0.f;
        #pragma unroll
        for (int d = 0; d < 28; ++d)
            s += wkv[c * 448 + 224 + h * 28 + d] * pw[(h * 28 + d) * 28 + co];
        M2[i] = s;
    }
}

// posT[h][j][i] = pos[h][i][j]
__global__ void gen_posT(const float* __restrict__ pos, float* __restrict__ posT) {
    int id = blockIdx.x * 256 + threadIdx.x;   // 32768
    int h = id >> 12, r = id & 4095, i = r >> 6, j = r & 63;
    posT[(h << 12) + (j << 6) + i] = pos[id];
}

// ---------------------------------------------------------------------------
// Strided matrix apply with TRANSPOSED matrix: out[m,c] = sum_k matT[k*M+m] in[k,c]
// ---------------------------------------------------------------------------
__global__ void dct_apply(const float* __restrict__ matT, const float* __restrict__ in,
                          float* __restrict__ out, int M, int Kd, int inner_n,
                          int stride_i_in, int kstride_in,
                          int stride_i_out, int mstride_out) {
    extern __shared__ float s_in[];  // [Kd][28]
    int bidx = blockIdx.x;
    int o = bidx / inner_n;
    int ii = bidx - o * inner_n;
    const float* bin = in + (size_t)o * HWC + (size_t)ii * stride_i_in;
    float* bout = out + (size_t)o * HWC + (size_t)ii * stride_i_out;
    int tot = Kd * C_;
    for (int e = threadIdx.x; e < tot; e += blockDim.x) {
        int k = e / C_;
        int c = e - k * C_;
        s_in[e] = bin[k * kstride_in + c];
    }
    __syncthreads();
    int m = threadIdx.x;
    if (m < M) {
        float4 acc[7];
        #pragma unroll
        for (int q = 0; q < 7; ++q) acc[q] = make_float4(0.f, 0.f, 0.f, 0.f);
        for (int k = 0; k < Kd; ++k) {
            float d = matT[k * M + m];   // coalesced across lanes
            const float4* row = (const float4*)(s_in + k * C_);
            #pragma unroll
            for (int q = 0; q < 7; ++q) {
                float4 v = row[q];
                acc[q].x += d * v.x; acc[q].y += d * v.y;
                acc[q].z += d * v.z; acc[q].w += d * v.w;
            }
        }
        float4* orow = (float4*)(bout + (size_t)m * mstride_out);
        #pragma unroll
        for (int q = 0; q < 7; ++q) orow[q] = acc[q];
    }
}

// ---------------------------------------------------------------------------
// Spectral DCT attention — Gram-matrix formulation, 256 threads / patch.
// (unchanged)
// ---------------------------------------------------------------------------
__global__ __launch_bounds__(256, 4) void spec_attn(
    const float* __restrict__ xdct, const float* __restrict__ wq,
    const float* __restrict__ wk, const float* __restrict__ wv,
    const float* __restrict__ rescale, const float* __restrict__ pw,
    const float* __restrict__ pb, float* __restrict__ xlow) {
    __shared__ __align__(16) float smem[9780];
    float* sX  = smem;             // [64][29] = 1856
    float* sG  = sX + 1856;        // 784
    float* sWq = sG + 784;         // 784
    float* sWk = sWq + 784;        // 784
    float* sWv = sWk + 784;        // 784
    float* sPw = sWv + 784;        // 784
    float* sA  = sPw + 784;        // 784
    float* sB  = sA + 784;         // 784
    float* sP  = sB + 784;         // [28][29] = 812
    float* sM3 = sP + 812;         // 784
    float* sR  = sM3 + 784;        // 784
    float* sqn = sR + 784;         // 28
    float* skn = sqn + 28;         // 28

    int t = threadIdx.x;
    int blk = blockIdx.x;
    int b = blk / 1280;
    int r = blk - b * 1280;
    int bh = r / 40;
    int bw = r - bh * 40;
    const float* base = xdct + ((size_t)((b * 256 + bh * 8) * 320 + bw * 8)) * 28;

    for (int e = t; e < 1792; e += 256) {
        int m = e / 28, c = e - m * 28;
        sX[m * 29 + c] = base[((m >> 3) * 320 + (m & 7)) * 28 + c];
    }
    for (int e = t; e < 784; e += 256) sR[e] = 0.f;
    __syncthreads();

    for (int e = t; e < 784; e += 256) {
        int c = e / 28, c2 = e - c * 28;
        float a0 = 0.f, a1 = 0.f, a2 = 0.f, a3 = 0.f;
        #pragma unroll 4
        for (int m = 0; m < 64; m += 4) {
            a0 += sX[m * 29 + c] * sX[m * 29 + c2];
            a1 += sX[(m + 1) * 29 + c] * sX[(m + 1) * 29 + c2];
            a2 += sX[(m + 2) * 29 + c] * sX[(m + 2) * 29 + c2];
            a3 += sX[(m + 3) * 29 + c] * sX[(m + 3) * 29 + c2];
        }
        sG[e] = (a0 + a1) + (a2 + a3);
    }
    __syncthreads();

    for (int h = 0; h < 8; ++h) {
        for (int e = t; e < 784; e += 256) {
            int c = e / 28, d = e - c * 28;
            sWq[e] = wq[c * 224 + h * 28 + d];
            sWk[e] = wk[c * 224 + h * 28 + d];
            sWv[e] = wv[c * 224 + h * 28 + d];
            sPw[e] = pw[h * 784 + e];
        }
        __syncthreads();
        for (int tile = t; tile < 392; tile += 256) {
            int isB = tile >= 196;
            int tt = isB ? tile - 196 : tile;
            int c = tt / 7, d4 = (tt - c * 7) * 4;
            const float* W = isB ? sWk : sWq;
            float ax = 0.f, ay = 0.f, az = 0.f, aw = 0.f;
            #pragma unroll
            for (int c2 = 0; c2 < 28; ++c2) {
                float g = sG[c * 28 + c2];
                const float4 w4 = *(const float4*)(W + c2 * 28 + d4);
                ax += g * w4.x; ay += g * w4.y; az += g * w4.z; aw += g * w4.w;
            }
            float* dst = (isB ? sB : sA) + c * 28 + d4;
            *(float4*)dst = make_float4(ax, ay, az, aw);
        }
        __syncthreads();
        if (t < 28) {
            float s = 0.f;
            #pragma unroll
            for (int c = 0; c < 28; ++c) s += sWq[c * 28 + t] * sA[c * 28 + t];
            sqn[t] = fmaxf(sqrtf(s), 1e-12f);
        } else if (t >= 32 && t < 60) {
            int d = t - 32;
            float s = 0.f;
            #pragma unroll
            for (int c = 0; c < 28; ++c) s += sWk[c * 28 + d] * sB[c * 28 + d];
            skn[d] = fmaxf(sqrtf(s), 1e-12f);
        }
        __syncthreads();
        float resc = rescale[h];
        for (int e = t; e < 784; e += 256) {
            int d = e / 28, ee = e - d * 28;
            float s = 0.f;
            #pragma unroll
            for (int c = 0; c < 28; ++c) s += sWq[c * 28 + d] * sB[c * 28 + ee];
            sP[d * 29 + ee] = __expf(s * resc / (sqn[d] * skn[ee]));
        }
        __syncthreads();
        if (t < 28) {
            float s = 0.f;
            #pragma unroll
            for (int ee = 0; ee < 28; ++ee) s += sP[t * 29 + ee];
            float inv = 1.0f / s;
            #pragma unroll
            for (int ee = 0; ee < 28; ++ee) sP[t * 29 + ee] *= inv;
        }
        __syncthreads();
        for (int id = t; id < 784; id += 256) {
            int ee = id / 28, co = id - ee * 28;
            float a0 = 0.f, a1 = 0.f;
            #pragma unroll 2
            for (int d = 0; d < 28; d += 2) {
                a0 += sP[d * 29 + ee] * sPw[d * 28 + co];
                a1 += sP[(d + 1) * 29 + ee] * sPw[(d + 1) * 28 + co];
            }
            sM3[id] = a0 + a1;
        }
        __syncthreads();
        for (int id = t; id < 784; id += 256) {
            int c = id / 28, co = id - c * 28;
            float a0 = 0.f, a1 = 0.f;
            #pragma unroll 2
            for (int e = 0; e < 28; e += 2) {
                a0 += sWv[c * 28 + e] * sM3[e * 28 + co];
                a1 += sWv[c * 28 + e + 1] * sM3[(e + 1) * 28 + co];
            }
            sR[id] += a0 + a1;
        }
        __syncthreads();
    }
    float* outp = xlow + ((size_t)((b * 256 + bh * 8) * 320 + bw * 8)) * 28;
    for (int id = t; id < 1792; id += 256) {
        int m = id / 28, co = id - m * 28;
        float s = pb[co];
        #pragma unroll
        for (int c = 0; c < 28; ++c) s += sX[m * 29 + c] * sR[c * 28 + co];
        outp[((m >> 3) * 320 + (m & 7)) * 28 + co] = s;
    }
}

// ---------------------------------------------------------------------------
// y1 = gelu(pointwise-conv(x_dct))
// ---------------------------------------------------------------------------
__global__ __launch_bounds__(256) void hf_pw1(const float* __restrict__ xdct,
                                              const float* __restrict__ w,
                                              float* __restrict__ y1) {
    __shared__ float s_w[28][29];
    __shared__ float s_x[256][29];
    int t = threadIdx.x;
    for (int e = t; e < 784; e += 256) s_w[e / 28][e % 28] = w[e];
    size_t p0 = (size_t)blockIdx.x * 256;
    const float* src = xdct + p0 * 28;
    for (int e = t; e < 7168; e += 256) {
        int p = e / 28, c = e - p * 28;
        s_x[p][c] = src[e];
    }
    __syncthreads();
    float o[28];
    #pragma unroll
    for (int oo = 0; oo < 28; ++oo) {
        float a = 0.f;
        #pragma unroll
        for (int c = 0; c < 28; ++c) a += s_w[oo][c] * s_x[t][c];
        o[oo] = gelu_f(a);
    }
    __syncthreads();
    #pragma unroll
    for (int oo = 0; oo < 28; ++oo) s_x[t][oo] = o[oo];
    __syncthreads();
    float* dst = y1 + p0 * 28;
    for (int e = t; e < 7168; e += 256) {
        int p = e / 28, c = e - p * 28;
        dst[e] = s_x[p][c];
    }
}

// ---------------------------------------------------------------------------
// Depthwise 3x3 + gelu + residual + pointwise2 + gelu + residual + coef blend
// ---------------------------------------------------------------------------
__global__ __launch_bounds__(256) void hf_combine(
    const float* __restrict__ y1, const float* __restrict__ xdct,
    const float* __restrict__ xlow, const float* __restrict__ dww,
    const float* __restrict__ pw2, const float* __restrict__ coef,
    float* __restrict__ xout) {
    __shared__ float s_dw[252];
    __shared__ float s_pw[28][29];
    int t = threadIdx.x;
    for (int e = t; e < 252; e += 256) s_dw[e] = dww[e];
    for (int e = t; e < 784; e += 256) s_pw[e / 28][e % 28] = pw2[e];
    __syncthreads();
    int pix = blockIdx.x * 256 + t;
    int b = pix / 81920;
    int rem = pix - b * 81920;
    int y = rem / 320;
    int xx = rem - y * 320;
    float conv[28];
    #pragma unroll
    for (int c = 0; c < 28; ++c) conv[c] = 0.f;
    for (int dy = 0; dy < 3; ++dy) {
        int yy = y + dy - 1;
        if (yy < 0 || yy >= 256) continue;
        for (int dx = 0; dx < 3; ++dx) {
            int xq = xx + dx - 1;
            if (xq < 0 || xq >= 320) continue;
            const float* rp = y1 + ((size_t)(b * 256 + yy) * 320 + xq) * 28;
            #pragma unroll
            for (int c = 0; c < 28; ++c) conv[c] += s_dw[c * 9 + dy * 3 + dx] * rp[c];
        }
    }
    const float* xd = xdct + (size_t)pix * 28;
    const float* xl = xlow + (size_t)pix * 28;
    float xdr[28], xcv[28];
    #pragma unroll
    for (int c = 0; c < 28; ++c) {
        xdr[c] = xd[c];
        xcv[c] = gelu_f(conv[c]) + xdr[c];
    }
    float cf = coef[rem];
    float omc = 1.0f - cf;
    float* xo = xout + (size_t)pix * 28;
    #pragma unroll
    for (int oo = 0; oo < 28; ++oo) {
        float a = 0.f;
        #pragma unroll
        for (int c = 0; c < 28; ++c) a += s_pw[oo][c] * xcv[c];
        float xh = gelu_f(a) + xcv[oo];
        xo[oo] = cf * xl[oo] + omc * xh + xdr[oo];
    }
}

// ---------------------------------------------------------------------------
// Local windowed attention v6: 128 threads = 2 waves = 2 windows, 8 heads/wave.
// Same as v5 but NO min-waves clamp: the j-loop needs ~140 live VGPRs; forcing
// fewer (rounds 6/7) caused 150-300 MB of scratch spill traffic. Let the
// allocator pick; LDS stays at 14.3 KB so occupancy is VGPR-limited (~3 w/SIMD).
// ---------------------------------------------------------------------------
__global__ __launch_bounds__(128) void local_attn(
    const float* __restrict__ x, const float* __restrict__ G,
    const float* __restrict__ M2, const float* __restrict__ posT,
    const float* __restrict__ pb, float* __restrict__ outloc) {
    __shared__ float s_xw[2][1792];    // 14336 B
    int t = threadIdx.x;
    int wave = t >> 6, lane = t & 63;
    int win = blockIdx.x * 2 + wave;
    int b = win / 1280;
    int r = win - b * 1280;
    int wh = r / 40, wwi = r - wh * 40;
    int p_ = lane >> 3, q_ = lane & 7;
    const float* rowp = x + ((size_t)((b * 256 + wh * 8 + p_) * 320) + wwi * 8 + q_) * 28;
    float* sxm = s_xw[wave] + lane * 28;
    #pragma unroll
    for (int q4 = 0; q4 < 7; ++q4)
        ((float4*)sxm)[q4] = ((const float4*)rowp)[q4];
    __syncthreads();
    float acc[28];
    #pragma unroll
    for (int c = 0; c < 28; ++c) acc[c] = 0.f;
    const float* swbase = s_xw[wave];
    for (int h = 0; h < 8; ++h) {
        // ---- t1 = own_row @ G_h  (own row re-read from LDS; G wave-uniform) ----
        float t1[28];
        #pragma unroll
        for (int d = 0; d < 28; ++d) t1[d] = 0.f;
        const float* gh = G + h * 784;
        #pragma unroll
        for (int c = 0; c < 28; ++c) {
            float xc = sxm[c];
            const float4* gr = (const float4*)(gh + c * 28);
            #pragma unroll
            for (int q4 = 0; q4 < 7; ++q4) {
                float4 g4 = gr[q4];
                t1[4 * q4] += xc * g4.x; t1[4 * q4 + 1] += xc * g4.y;
                t1[4 * q4 + 2] += xc * g4.z; t1[4 * q4 + 3] += xc * g4.w;
            }
        }
        // ---- single-pass no-max softmax: S, u = sum_j exp(s_j) xw_j ----
        float S = 0.f;
        float u[28];
        #pragma unroll
        for (int c = 0; c < 28; ++c) u[c] = 0.f;
        const float* pbase = posT + (h << 12) + lane;
        for (int j = 0; j < 64; ++j) {
            const float4* rj = (const float4*)(swbase + j * 28);
            float4 r0 = rj[0], r1 = rj[1], r2 = rj[2], r3 = rj[3];
            float4 r4 = rj[4], r5 = rj[5], r6 = rj[6];
            float a0 = t1[0] * r0.x + t1[4] * r1.x + t1[8] * r2.x + t1[12] * r3.x
                     + t1[16] * r4.x + t1[20] * r5.x + t1[24] * r6.x;
            float a1 = t1[1] * r0.y + t1[5] * r1.y + t1[9] * r2.y + t1[13] * r3.y
                     + t1[17] * r4.y + t1[21] * r5.y + t1[25] * r6.y;
            float a2 = t1[2] * r0.z + t1[6] * r1.z + t1[10] * r2.z + t1[14] * r3.z
                     + t1[18] * r4.z + t1[22] * r5.z + t1[26] * r6.z;
            float a3 = t1[3] * r0.w + t1[7] * r1.w + t1[11] * r2.w + t1[15] * r3.w
                     + t1[19] * r4.w + t1[23] * r5.w + t1[27] * r6.w;
            float s = ((a0 + a1) + (a2 + a3)) + pbase[j << 6];
            float p = __expf(s);
            S += p;
            u[0] += p * r0.x; u[1] += p * r0.y; u[2] += p * r0.z; u[3] += p * r0.w;
            u[4] += p * r1.x; u[5] += p * r1.y; u[6] += p * r1.z; u[7] += p * r1.w;
            u[8] += p * r2.x; u[9] += p * r2.y; u[10] += p * r2.z; u[11] += p * r2.w;
            u[12] += p * r3.x; u[13] += p * r3.y; u[14] += p * r3.z; u[15] += p * r3.w;
            u[16] += p * r4.x; u[17] += p * r4.y; u[18] += p * r4.z; u[19] += p * r4.w;
            u[20] += p * r5.x; u[21] += p * r5.y; u[22] += p * r5.z; u[23] += p * r5.w;
            u[24] += p * r6.x; u[25] += p * r6.y; u[26] += p * r6.z; u[27] += p * r6.w;
        }
        float inv = 1.0f / S;
        // ---- acc += (u*inv) @ M2_h  (M2 wave-uniform from global) ----
        const float* mh = M2 + h * 784;
        #pragma unroll
        for (int c = 0; c < 28; ++c) {
            float uc = u[c] * inv;
            const float4* mr = (const float4*)(mh + c * 28);
            #pragma unroll
            for (int q4 = 0; q4 < 7; ++q4) {
                float4 m4 = mr[q4];
                acc[4 * q4] += uc * m4.x; acc[4 * q4 + 1] += uc * m4.y;
                acc[4 * q4 + 2] += uc * m4.z; acc[4 * q4 + 3] += uc * m4.w;
            }
        }
    }
    float* op = outloc + ((size_t)((b * 256 + wh * 8 + p_) * 320) + wwi * 8 + q_) * 28;
    #pragma unroll
    for (int q4 = 0; q4 < 7; ++q4) {
        float4 o4;
        o4.x = acc[4 * q4] + pb[4 * q4];
        o4.y = acc[4 * q4 + 1] + pb[4 * q4 + 1];
        o4.z = acc[4 * q4 + 2] + pb[4 * q4 + 2];
        o4.w = acc[4 * q4 + 3] + pb[4 * q4 + 3];
        ((float4*)op)[q4] = o4;
    }
}

// ---------------------------------------------------------------------------
// Fusion
// ---------------------------------------------------------------------------
__global__ __launch_bounds__(256) void fuse_k(
    const float* __restrict__ fd, const float* __restrict__ loc,
    const float* __restrict__ w, const float* __restrict__ bias,
    float* __restrict__ out) {
    __shared__ float s_w[28][57];
    __shared__ float s_b[28];
    int t = threadIdx.x;
    for (int e = t; e < 28 * 56; e += 256) s_w[e / 56][e % 56] = w[e];
    if (t < 28) s_b[t] = bias[t];
    __syncthreads();
    size_t pix = (size_t)blockIdx.x * 256 + t;
    const float* f = fd + pix * 28;
    const float* l = loc + pix * 28;
    float fr[28], lr[28];
    #pragma unroll
    for (int c = 0; c < 28; ++c) { fr[c] = f[c]; lr[c] = l[c]; }
    float* o = out + pix * 28;
    #pragma unroll
    for (int oo = 0; oo < 28; ++oo) {
        float a = s_b[oo];
        #pragma unroll
        for (int c = 0; c < 28; ++c) a += s_w[oo][c] * fr[c] + s_w[oo][28 + c] * lr[c];
        o[oo] = a;
    }
}

extern "C" void kernel_launch(void* const* d_in, const int* in_sizes, int n_in,
                              void* d_out, int out_size, void* d_ws, size_t ws_size,
                              hipStream_t stream) {
    const float* x         = (const float*)d_in[0];
    const float* spec_wq   = (const float*)d_in[1];
    const float* spec_wk   = (const float*)d_in[2];
    const float* spec_wv   = (const float*)d_in[3];
    const float* spec_resc = (const float*)d_in[4];
    const float* spec_pw   = (const float*)d_in[5];
    const float* spec_pb   = (const float*)d_in[6];
    const float* hf1_pw_w  = (const float*)d_in[7];
    const float* hf1_dw_w  = (const float*)d_in[8];
    const float* hf2_pw_w  = (const float*)d_in[9];
    const float* coef_emb  = (const float*)d_in[10];
    const float* loc_wq    = (const float*)d_in[11];
    const float* loc_wkv   = (const float*)d_in[12];
    const float* loc_pos   = (const float*)d_in[13];
    const float* loc_pw    = (const float*)d_in[14];
    const float* loc_pb    = (const float*)d_in[15];
    const float* fus_w     = (const float*)d_in[16];
    const float* fus_b     = (const float*)d_in[17];

    float* ws = (float*)d_ws;
    float* mDH  = ws;                       // 65536
    float* mDW  = mDH + 65536;              // 102400
    float* mDIH = mDW + 102400;             // 65536
    float* mDIW = mDIH + 65536;             // 102400
    float* locG = mDIW + 102400;            // 6272
    float* locM2 = locG + 6272;             // 6272
    float* posT = locM2 + 6272;             // 32768
    float* bufA = posT + 32768;             // 2*HWC each
    float* bufB = bufA + 2 * HWC;
    float* bufC = bufB + 2 * HWC;
    float* bufD = bufC + 2 * HWC;

    gen_mats<<<400, 256, 0, stream>>>(mDH, mDW, mDIH, mDIW);
    gen_locG<<<25, 256, 0, stream>>>(loc_wq, loc_wkv, locG);
    gen_locM2<<<25, 256, 0, stream>>>(loc_wkv, loc_pw, locM2);
    gen_posT<<<128, 256, 0, stream>>>(loc_pos, posT);

    // forward DCT
    dct_apply<<<640, 256, 256 * 28 * 4, stream>>>(mDH, x, bufA,
        256, 256, 320, 28, 8960, 28, 8960);
    dct_apply<<<512, 320, 320 * 28 * 4, stream>>>(mDW, bufA, bufB,
        320, 320, 256, 8960, 28, 8960, 28);

    // spectral attention -> x_low (bufC)
    spec_attn<<<2560, 256, 0, stream>>>(bufB, spec_wq, spec_wk, spec_wv,
                                        spec_resc, spec_pw, spec_pb, bufC);
    // high-frequency path
    hf_pw1<<<640, 256, 0, stream>>>(bufB, hf1_pw_w, bufA);
    hf_combine<<<640, 256, 0, stream>>>(bufA, bufB, bufC, hf1_dw_w, hf2_pw_w,
                                        coef_emb, bufD);
    // inverse DCT: x_out (bufD) -> out_fd (bufC)
    dct_apply<<<640, 256, 256 * 28 * 4, stream>>>(mDIH, bufD, bufA,
        256, 256, 320, 28, 8960, 28, 8960);
    dct_apply<<<512, 320, 320 * 28 * 4, stream>>>(mDIW, bufA, bufC,
        320, 320, 256, 8960, 28, 8960, 28);

    // local windowed attention -> bufB
    local_attn<<<1280, 128, 0, stream>>>(x, locG, locM2, posT, loc_pb, bufB);

    // fusion -> output
    fuse_k<<<640, 256, 0, stream>>>(bufC, bufB, fus_w, fus_b, (float*)d_out);
}